// Round 1
// baseline (54481.927 us; speedup 1.0000x reference)
//
#include <hip/hip_runtime.h>

// Persistent 8-team (one per XCD, blockIdx%8) attention-GRU scan.
// 256 blocks x 256 threads; team = 32 blocks = 128 waves, owns 16 batch rows.
// All cross-block sync is team-local (instance-counter barriers in ws).
// GEMMs: bf16 MFMA 16x16x32, M=16 (batches), weights [N][K] row-major.

#define MAGIC 0x13579BDFu

typedef __attribute__((ext_vector_type(8))) short bf16x8;
typedef __attribute__((ext_vector_type(4))) float f32x4;
typedef unsigned short u16;
typedef unsigned int u32;

// ---- workspace layout (bytes) ----
#define OFF_CTRL 0            // 8 teams * 16KB barrier control
#define OFF_AW   131072       // attn_W bf16 [512][1024]   1 MiB
#define OFF_CW   1179648      // comb_W bf16 [512][1024]   1 MiB
#define OFF_WIH  2228224      // w_ih  bf16 [1536][512]  1.5 MiB
#define OFF_WHH  3801088      // w_hh  bf16 [1536][512]  1.5 MiB
#define OFF_OW   5373952      // out_W bf16 [512][512]   0.5 MiB
#define OFF_XBF  5898240      // x bf16 [128][512][512]   64 MiB
#define OFF_XE   73007104     // inp(t) bf16 [128][512]
#define OFF_HB   73138176     // h bf16 [128][512]
#define OFF_H    73269248     // h f32 [128][512]
#define OFF_S    73531392     // scores f32 [128][512]
#define OFF_APPL 73793536     // applied bf16 [128][512]
#define OFF_G    73924608     // g bf16 [128][512]
#define OFF_GH   74055680     // gh f32 [128][1536]
#define OFF_GI   74842112     // gi f32 [128][1536]
#define WS_NEED  75628544

__device__ __forceinline__ float bf2f(u16 v) {
  union { u32 u; float f; } x; x.u = ((u32)v) << 16; return x.f;
}
__device__ __forceinline__ u16 f2bf(float f) {
  union { float f; u32 u; } x; x.f = f;
  u32 r = (x.u + 0x7fffu + ((x.u >> 16) & 1u)) >> 16;
  return (u16)r;
}
__device__ __forceinline__ float sigmoidf_(float v) { return 1.f / (1.f + __expf(-v)); }
__device__ __forceinline__ float tanhf_(float v) {
  v = fminf(fmaxf(v, -15.f), 15.f);
  float e2 = __expf(2.f * v);
  return (e2 - 1.f) / (e2 + 1.f);
}

// team-local barrier: one-shot instance counters (re-poisoned->rezeroed each launch)
__device__ __forceinline__ void team_barrier(u32* cnts, int k) {
  __syncthreads();
  if (threadIdx.x == 0) {
    u32* c = cnts + k;
    __threadfence();                       // release my block's writes (device scope)
    atomicAdd(c, 1u);
    while (__hip_atomic_load(c, __ATOMIC_RELAXED, __HIP_MEMORY_SCOPE_AGENT) < 32u)
      __builtin_amdgcn_s_sleep(2);
    __threadfence();                       // acquire other blocks' writes
  }
  __syncthreads();
}

extern "C" __global__ void __launch_bounds__(256, 1)
rnn_fused(const float* __restrict__ x, const float* __restrict__ attn_W,
          const float* __restrict__ attn_b, const float* __restrict__ comb_W,
          const float* __restrict__ comb_b, const float* __restrict__ w_ih,
          const float* __restrict__ w_hh, const float* __restrict__ b_ih,
          const float* __restrict__ b_hh, const float* __restrict__ out_W,
          const float* __restrict__ out_b, float* __restrict__ out,
          char* __restrict__ ws)
{
  const int tid  = threadIdx.x;
  const int lane = tid & 63;
  const int warp = tid >> 6;
  const int team = blockIdx.x & 7;     // XCD-round-robin heuristic (correct regardless)
  const int tb   = blockIdx.x >> 3;    // 0..31 block within team
  const int W    = tb * 4 + warp;      // team wave id 0..127
  const int tt   = tb * 256 + tid;     // team thread id 0..8191
  const int gb0  = team * 16;          // first global batch row of team

  u32* ctrl = (u32*)ws + team * 4096;  // 16KB per team
  u32* flag = ctrl;
  u32* cnts = ctrl + 16;

  u16*   AW   = (u16*)(ws + OFF_AW);
  u16*   CWb  = (u16*)(ws + OFF_CW);
  u16*   WIH  = (u16*)(ws + OFF_WIH);
  u16*   WHH  = (u16*)(ws + OFF_WHH);
  u16*   OWb  = (u16*)(ws + OFF_OW);
  u16*   XBF  = (u16*)(ws + OFF_XBF);
  u16*   XE   = (u16*)(ws + OFF_XE);
  u16*   HB   = (u16*)(ws + OFF_HB);
  float* Hf   = (float*)(ws + OFF_H);
  float* Sf   = (float*)(ws + OFF_S);
  u16*   APPL = (u16*)(ws + OFF_APPL);
  u16*   Gb   = (u16*)(ws + OFF_G);
  float* GH   = (float*)(ws + OFF_GH);
  float* GI   = (float*)(ws + OFF_GI);

  // ---- init handshake: block 0 of team zeroes counters, sets magic flag ----
  if (tb == 0) {
    for (int i = 16 + tid; i < 4096; i += 256) ctrl[i] = 0u;
    __syncthreads();
    if (tid == 0) { __threadfence(); atomicExch(flag, MAGIC); }
  }
  if (tid == 0) {
    while (__hip_atomic_load(flag, __ATOMIC_RELAXED, __HIP_MEMORY_SCOPE_AGENT) != MAGIC)
      __builtin_amdgcn_s_sleep(2);
    __threadfence();
  }
  __syncthreads();

  // ---- phase 0: bf16 conversions (weights redundantly per team: benign same-value races) ----
  for (int i = tt; i < 512 * 1024; i += 8192) AW[i]  = f2bf(attn_W[i]);
  for (int i = tt; i < 512 * 1024; i += 8192) CWb[i] = f2bf(comb_W[i]);
  for (int i = tt; i < 1536 * 512; i += 8192) WIH[i] = f2bf(w_ih[i]);
  for (int i = tt; i < 1536 * 512; i += 8192) WHH[i] = f2bf(w_hh[i]);
  for (int i = tt; i < 512 * 512;  i += 8192) OWb[i] = f2bf(out_W[i]);
  {
    const int base = gb0 * (512 * 512);
    for (int i = tt; i < 16 * 512 * 512; i += 8192) XBF[base + i] = f2bf(x[base + i]);
  }
  Hf[gb0 * 512 + tt] = 0.f;
  HB[gb0 * 512 + tt] = 0;
  XE[gb0 * 512 + tt] = XBF[(gb0 * 512 + tt) * 512];   // x[:, :, t=0]

  int bk = 0;
  team_barrier(cnts, bk++);

  const int r  = lane & 15;      // A-row (m) / B-row (n) / C-col index
  const int q  = lane >> 4;      // quad
  const int q8 = q * 8;          // k offset within 32-wide MFMA step

  for (int t = 0; t < 512; ++t) {
    // ---- stage A: S = [xe|hb] @ attn_W^T + attn_b  AND  gh = hb @ w_hh^T + b_hh ----
    if (W < 32) {
      const int n0 = W * 16;
      f32x4 acc = {0.f, 0.f, 0.f, 0.f};
      const u16* xeB = XE + (gb0 + r) * 512 + q8;
      const u16* hbB = HB + (gb0 + r) * 512 + q8;
      const u16* wB  = AW + (n0 + r) * 1024 + q8;
      for (int k0 = 0; k0 < 512; k0 += 32) {
        bf16x8 a = *(const bf16x8*)(xeB + k0);
        bf16x8 b = *(const bf16x8*)(wB + k0);
        acc = __builtin_amdgcn_mfma_f32_16x16x32_bf16(a, b, acc, 0, 0, 0);
      }
      for (int k0 = 0; k0 < 512; k0 += 32) {
        bf16x8 a = *(const bf16x8*)(hbB + k0);
        bf16x8 b = *(const bf16x8*)(wB + 512 + k0);
        acc = __builtin_amdgcn_mfma_f32_16x16x32_bf16(a, b, acc, 0, 0, 0);
      }
      const float bias = attn_b[n0 + r];
#pragma unroll
      for (int i = 0; i < 4; ++i)
        Sf[(gb0 + q * 4 + i) * 512 + n0 + r] = acc[i] + bias;
    } else {
      const int n0 = (W - 32) * 16;
      f32x4 acc = {0.f, 0.f, 0.f, 0.f};
      const u16* hbB = HB + (gb0 + r) * 512 + q8;
      const u16* wB  = WHH + (n0 + r) * 512 + q8;
      for (int k0 = 0; k0 < 512; k0 += 32) {
        bf16x8 a = *(const bf16x8*)(hbB + k0);
        bf16x8 b = *(const bf16x8*)(wB + k0);
        acc = __builtin_amdgcn_mfma_f32_16x16x32_bf16(a, b, acc, 0, 0, 0);
      }
      const float bias = b_hh[n0 + r];
#pragma unroll
      for (int i = 0; i < 4; ++i)
        GH[(gb0 + q * 4 + i) * 1536 + n0 + r] = acc[i] + bias;
    }
    team_barrier(cnts, bk++);

    // ---- stage C: per-row softmax (wave-redundant) + applied = P @ x[b] ----
    {
      const int gb = gb0 + (W >> 3);
      const int tp = ((W & 7) << 6) + lane;
      float s0[8], p[8];
#pragma unroll
      for (int k = 0; k < 8; ++k) s0[k] = Sf[gb * 512 + (k << 6) + lane];
      float mx = s0[0];
#pragma unroll
      for (int k = 1; k < 8; ++k) mx = fmaxf(mx, s0[k]);
#pragma unroll
      for (int off = 32; off; off >>= 1) mx = fmaxf(mx, __shfl_xor(mx, off, 64));
      float sum = 0.f;
#pragma unroll
      for (int k = 0; k < 8; ++k) { p[k] = __expf(s0[k] - mx); sum += p[k]; }
#pragma unroll
      for (int off = 32; off; off >>= 1) sum += __shfl_xor(sum, off, 64);
      const float inv = 1.f / sum;
#pragma unroll
      for (int k = 0; k < 8; ++k) p[k] *= inv;

      float acc = 0.f;
      const u16* xb = XBF + gb * (512 * 512) + tp;
      for (int mb = 0; mb < 8; ++mb) {
#pragma unroll 8
        for (int j = 0; j < 64; ++j) {
          const float pm = __shfl(p[mb], j, 64);
          acc += pm * bf2f(xb[((mb << 6) + j) << 9]);
        }
      }
      APPL[gb * 512 + tp] = f2bf(acc);
    }
    team_barrier(cnts, bk++);

    // ---- stage D: g = relu([xe|applied] @ comb_W^T + comb_b) ----
    if (W < 32) {
      const int n0 = W * 16;
      f32x4 acc = {0.f, 0.f, 0.f, 0.f};
      const u16* xeB = XE + (gb0 + r) * 512 + q8;
      const u16* apB = APPL + (gb0 + r) * 512 + q8;
      const u16* wB  = CWb + (n0 + r) * 1024 + q8;
      for (int k0 = 0; k0 < 512; k0 += 32) {
        bf16x8 a = *(const bf16x8*)(xeB + k0);
        bf16x8 b = *(const bf16x8*)(wB + k0);
        acc = __builtin_amdgcn_mfma_f32_16x16x32_bf16(a, b, acc, 0, 0, 0);
      }
      for (int k0 = 0; k0 < 512; k0 += 32) {
        bf16x8 a = *(const bf16x8*)(apB + k0);
        bf16x8 b = *(const bf16x8*)(wB + 512 + k0);
        acc = __builtin_amdgcn_mfma_f32_16x16x32_bf16(a, b, acc, 0, 0, 0);
      }
      const float bias = comb_b[n0 + r];
#pragma unroll
      for (int i = 0; i < 4; ++i)
        Gb[(gb0 + q * 4 + i) * 512 + n0 + r] = f2bf(fmaxf(acc[i] + bias, 0.f));
    }
    team_barrier(cnts, bk++);

    // ---- stage E: gi = g @ w_ih^T + b_ih ----
    if (W < 96) {
      const int n0 = W * 16;
      f32x4 acc = {0.f, 0.f, 0.f, 0.f};
      const u16* gB = Gb + (gb0 + r) * 512 + q8;
      const u16* wB = WIH + (n0 + r) * 512 + q8;
      for (int k0 = 0; k0 < 512; k0 += 32) {
        bf16x8 a = *(const bf16x8*)(gB + k0);
        bf16x8 b = *(const bf16x8*)(wB + k0);
        acc = __builtin_amdgcn_mfma_f32_16x16x32_bf16(a, b, acc, 0, 0, 0);
      }
      const float bias = b_ih[n0 + r];
#pragma unroll
      for (int i = 0; i < 4; ++i)
        GI[(gb0 + q * 4 + i) * 1536 + n0 + r] = acc[i] + bias;
    }
    team_barrier(cnts, bk++);

    // ---- stage F: GRU pointwise; refresh h, hb, xe(t+1) ----
    {
      const int lb = tt >> 9, j = tt & 511;
      const int gb = gb0 + lb;
      const float ir  = GI[gb * 1536 + j];
      const float iz  = GI[gb * 1536 + 512 + j];
      const float inn = GI[gb * 1536 + 1024 + j];
      const float hr  = GH[gb * 1536 + j];
      const float hz  = GH[gb * 1536 + 512 + j];
      const float hn  = GH[gb * 1536 + 1024 + j];
      const float rg = sigmoidf_(ir + hr);
      const float zg = sigmoidf_(iz + hz);
      const float ng = tanhf_(inn + rg * hn);
      const float hp = Hf[gb * 512 + j];
      const float hnew = (1.f - zg) * ng + zg * hp;
      Hf[gb * 512 + j] = hnew;
      HB[gb * 512 + j] = f2bf(hnew);
      if (t < 511) XE[gb * 512 + j] = XBF[(gb * 512 + j) * 512 + t + 1];
    }
    team_barrier(cnts, bk++);
  }

  // ---- epilogue: out = h @ out_W^T + out_b ----
  if (W < 32) {
    const int n0 = W * 16;
    f32x4 acc = {0.f, 0.f, 0.f, 0.f};
    const u16* hB = HB + (gb0 + r) * 512 + q8;
    const u16* wB = OWb + (n0 + r) * 512 + q8;
    for (int k0 = 0; k0 < 512; k0 += 32) {
      bf16x8 a = *(const bf16x8*)(hB + k0);
      bf16x8 b = *(const bf16x8*)(wB + k0);
      acc = __builtin_amdgcn_mfma_f32_16x16x32_bf16(a, b, acc, 0, 0, 0);
    }
    const float bias = out_b[n0 + r];
#pragma unroll
    for (int i = 0; i < 4; ++i)
      out[(gb0 + q * 4 + i) * 512 + n0 + r] = acc[i] + bias;
  }
}

extern "C" void kernel_launch(void* const* d_in, const int* in_sizes, int n_in,
                              void* d_out, int out_size, void* d_ws, size_t ws_size,
                              hipStream_t stream) {
  if (ws_size < (size_t)WS_NEED) return;  // need ~75.7 MB scratch
  rnn_fused<<<dim3(256), dim3(256), 0, stream>>>(
      (const float*)d_in[0], (const float*)d_in[1], (const float*)d_in[2],
      (const float*)d_in[3], (const float*)d_in[4], (const float*)d_in[5],
      (const float*)d_in[6], (const float*)d_in[7], (const float*)d_in[8],
      (const float*)d_in[9], (const float*)d_in[10],
      (float*)d_out, (char*)d_ws);
}

// Round 2
// 48095.004 us; speedup vs baseline: 1.1328x; 1.1328x over previous
//
#include <hip/hip_runtime.h>

// Persistent 8-team attention-GRU scan, register-resident x.
// 256 blocks x 256 threads, 1 block/CU. team = blockIdx%8 (32 blocks, 16 batches).
// Pair of blocks (tb>>1) owns batch gb0+(tb>>1); each holds one m-half (256 rows)
// of x[b] in VGPRs as packed f16 pairs (64 uint4 per thread).
// Roles: blocks 0..7 = attn/comb/wih+GRU GEMM waves; blocks 8..15 = whh; all = softmax+applied.
// Sync: monotonic token flags (store t+1, poll >= t+1) in ws ctrl region.

typedef unsigned short u16;
typedef unsigned int u32;
typedef _Float16 h2 __attribute__((ext_vector_type(2)));
typedef _Float16 f16x8 __attribute__((ext_vector_type(8)));
typedef __attribute__((ext_vector_type(4))) float f32x4;

#define MAGIC 0x13579BDFu

// ---- workspace layout (bytes) ----
#define OFF_AW   65536      // attn_W f16 [512][1024] 1 MiB
#define OFF_CW   1114112    // comb_W f16 [512][1024] 1 MiB
#define OFF_WIH  2162688    // w_ih  f16 [1536][512] 1.5 MiB
#define OFF_WHH  3735552    // w_hh  f16 [1536][512] 1.5 MiB
#define OFF_OW   5308416    // out_W f16 [512][512] 0.5 MiB
#define OFF_HB   5832704    // h f16 [128][512]
#define OFF_SF   5963776    // scores f32 [128][512]
#define OFF_APH0 6225920    // applied half0 partial f32 [128][512]
#define OFF_APH1 6488064    // applied half1 partial f32 [128][512]
#define OFF_GB   6750208    // g f16 [128][512]
#define OFF_GH   6881280    // gh f32 [128][1536]
#define OFF_XT   7667712    // x^T f16 [128][512 t][512 m] 64 MiB
#define WS_NEED  74776576

// flag slot bases (u32 index into per-team ctrl[1024])
#define FS_S   64
#define FS_C   96
#define FS_G   128
#define FS_GH  160
#define FS_H   192
#define FS_RDY 224

__device__ __forceinline__ float sigmoidf_(float v) { return 1.f / (1.f + __expf(-v)); }
__device__ __forceinline__ float tanhf_(float v) {
  v = fminf(fmaxf(v, -15.f), 15.f);
  float e2 = __expf(2.f * v);
  return (e2 - 1.f) / (e2 + 1.f);
}

__device__ __forceinline__ void flag_arrive(u32* ctrl, int fs, int slot, u32 tok) {
  __syncthreads();                      // drain all block waves' stores (vmcnt0 before barrier)
  if (threadIdx.x == 0) { __threadfence(); atomicMax(ctrl + fs + slot, tok); }
}
__device__ __forceinline__ void flag_wait(u32* ctrl, int fs, int n, u32 tok, int lane) {
  if (tok == 0u) return;
  u32* p = ctrl + fs;
  for (;;) {
    u32 v = tok;
    if (lane < n) v = __hip_atomic_load(p + lane, __ATOMIC_RELAXED, __HIP_MEMORY_SCOPE_AGENT);
    if (__all((int)(v >= tok))) break;
  }
  __threadfence();                      // acquire
}

#define MFMA(a, b, c) __builtin_amdgcn_mfma_f32_16x16x32_f16((a), (b), (c), 0, 0, 0)

extern "C" __global__ void __launch_bounds__(256, 1)
rnn_fused(const float* __restrict__ x, const float* __restrict__ attn_W,
          const float* __restrict__ attn_b, const float* __restrict__ comb_W,
          const float* __restrict__ comb_b, const float* __restrict__ w_ih,
          const float* __restrict__ w_hh, const float* __restrict__ b_ih,
          const float* __restrict__ b_hh, const float* __restrict__ out_W,
          const float* __restrict__ out_b, float* __restrict__ out,
          char* __restrict__ ws)
{
  const int tid  = threadIdx.x;
  const int lane = tid & 63;
  const int warp = tid >> 6;
  const int team = blockIdx.x & 7;
  const int tb   = blockIdx.x >> 3;     // 0..31 within team
  const int tt   = tb * 256 + tid;      // team thread id
  const int gb0  = team * 16;
  const int lb   = tb >> 1;             // pair index -> batch
  const int half = tb & 1;              // m-half of x held by this block
  const int b    = gb0 + lb;            // this block's batch (x holder / stage C)
  const int m0h  = half * 256;

  u32* ctrl = (u32*)ws + team * 1024;   // 4 KB per team

  u16*   AW  = (u16*)(ws + OFF_AW);
  u16*   CW  = (u16*)(ws + OFF_CW);
  u16*   WIH = (u16*)(ws + OFF_WIH);
  u16*   WHH = (u16*)(ws + OFF_WHH);
  u16*   OW  = (u16*)(ws + OFF_OW);
  u16*   HB  = (u16*)(ws + OFF_HB);
  float* Sf  = (float*)(ws + OFF_SF);
  float* AP0 = (float*)(ws + OFF_APH0);
  float* AP1 = (float*)(ws + OFF_APH1);
  u16*   GB  = (u16*)(ws + OFF_GB);
  float* GH  = (float*)(ws + OFF_GH);
  u16*   XT  = (u16*)(ws + OFF_XT);

  __shared__ char smem[16704];
  float* tbuf   = (float*)smem;             // [64][65] f32, phase 0 transpose only
  u32*   pLDS   = (u32*)smem;               // [128] packed f16 p-pairs (this block's m-half)
  float* redbuf = (float*)(smem + 512);     // [4][512] stage C partials
  float* rbuf   = (float*)(smem + 8704);    // [8] softmax reduce scratch

  // ---- init handshake (per team): block 0 zeroes ctrl, sets magic ----
  if (tb == 0) {
    for (int i = 1 + tid; i < 1024; i += 256) ctrl[i] = 0u;
    __syncthreads();
    if (tid == 0) { __threadfence(); atomicExch(ctrl, MAGIC); }
  }
  if (tid == 0) {
    while (__hip_atomic_load(ctrl, __ATOMIC_RELAXED, __HIP_MEMORY_SCOPE_AGENT) != MAGIC) {}
    __threadfence();
  }
  __syncthreads();

  // ---- phase 0a: weights -> f16 (team-redundant, same-value benign races) ----
  for (int i = tt; i < 512 * 1024; i += 8192) AW[i]  = __builtin_bit_cast(u16, (_Float16)attn_W[i]);
  for (int i = tt; i < 512 * 1024; i += 8192) CW[i]  = __builtin_bit_cast(u16, (_Float16)comb_W[i]);
  for (int i = tt; i < 1536 * 512; i += 8192) WIH[i] = __builtin_bit_cast(u16, (_Float16)w_ih[i]);
  for (int i = tt; i < 1536 * 512; i += 8192) WHH[i] = __builtin_bit_cast(u16, (_Float16)w_hh[i]);
  for (int i = tt; i < 512 * 512;  i += 8192) OW[i]  = __builtin_bit_cast(u16, (_Float16)out_W[i]);
  HB[(size_t)gb0 * 512 + tt] = 0;   // h0 = 0 (f16 +0)

  // ---- phase 0b: transpose this block's m-half of x[b] into XT[b][t][m] (f16) ----
  {
    const float* xb  = x  + (size_t)b * 512 * 512;
    u16*         xtB = XT + (size_t)b * 512 * 512;
    for (int mt = 0; mt < 4; ++mt) {
      for (int ct = 0; ct < 8; ++ct) {
        for (int rr = warp; rr < 64; rr += 4)
          tbuf[rr * 65 + lane] = xb[(size_t)(m0h + mt * 64 + rr) * 512 + ct * 64 + lane];
        __syncthreads();
        for (int rr = warp; rr < 64; rr += 4)
          xtB[(size_t)(ct * 64 + rr) * 512 + m0h + mt * 64 + lane] =
              __builtin_bit_cast(u16, (_Float16)tbuf[lane * 65 + rr]);
        __syncthreads();
      }
    }
  }

  flag_arrive(ctrl, FS_RDY, tb, 1u);
  flag_wait(ctrl, FS_RDY, 32, 1u, lane);

  // ---- phase 0c: register-resident x: 8 tc-rows (tc=lane*8+r) x 64 m (warp's quarter) ----
  uint4 xr4[64];
  {
    const u16* base = XT + (size_t)b * 262144 + m0h + warp * 64;
#pragma unroll
    for (int r = 0; r < 8; ++r) {
      const uint4* row = (const uint4*)(base + (size_t)(lane * 8 + r) * 512);
#pragma unroll
      for (int jj = 0; jj < 8; ++jj) xr4[r * 8 + jj] = row[jj];
    }
  }

  const int  r16 = lane & 15, q = lane >> 4, q8 = q * 8;
  const bool isA = (tb < 8), isW = (tb >= 8 && tb < 16);
  const int  W4 = ((tb < 8) ? tb : tb - 8) * 4 + warp;   // 0..31 for role blocks
  const int  n0 = W4 * 16;

  float biasA = 0.f, biasD = 0.f, biasI0 = 0.f, biasI1 = 0.f, biasI2 = 0.f,
        biasH0 = 0.f, biasH1 = 0.f, biasH2 = 0.f, biasO = 0.f;
  if (isA) {
    biasA = attn_b[n0 + r16]; biasD = comb_b[n0 + r16];
    biasI0 = b_ih[n0 + r16]; biasI1 = b_ih[512 + n0 + r16]; biasI2 = b_ih[1024 + n0 + r16];
    biasO = out_b[n0 + r16];
  }
  if (isW) {
    biasH0 = b_hh[n0 + r16]; biasH1 = b_hh[512 + n0 + r16]; biasH2 = b_hh[1024 + n0 + r16];
  }

  float hreg[4] = {0.f, 0.f, 0.f, 0.f};   // EF waves: h for (batch q*4+i, col n0+r16)

  for (int t = 0; t < 512; ++t) {
    const u32 tok = (u32)(t + 1);

    if (isA) {
      flag_wait(ctrl, FS_H, 8, (u32)t, lane);
      // stage A: S = [x(:,t) | h] @ attn_W^T + attn_b
      f32x4 acc = {0.f, 0.f, 0.f, 0.f};
      const u16* aXp = XT + (size_t)(gb0 + r16) * 262144 + (size_t)t * 512 + q8;
      const u16* aHp = HB + (size_t)(gb0 + r16) * 512 + q8;
      const u16* bWp = AW + (size_t)(n0 + r16) * 1024 + q8;
#pragma unroll 4
      for (int k0 = 0; k0 < 512; k0 += 32)
        acc = MFMA(*(const f16x8*)(aXp + k0), *(const f16x8*)(bWp + k0), acc);
#pragma unroll 4
      for (int k0 = 0; k0 < 512; k0 += 32)
        acc = MFMA(*(const f16x8*)(aHp + k0), *(const f16x8*)(bWp + 512 + k0), acc);
#pragma unroll
      for (int i = 0; i < 4; ++i)
        Sf[(size_t)(gb0 + q * 4 + i) * 512 + n0 + r16] = acc[i] + biasA;
      flag_arrive(ctrl, FS_S, tb, tok);
    } else if (isW) {
      flag_wait(ctrl, FS_H, 8, (u32)t, lane);
      // gh = h @ w_hh^T + b_hh (3 gate tiles, shared A-fragment)
      f32x4 a0 = {0.f,0.f,0.f,0.f}, a1 = {0.f,0.f,0.f,0.f}, a2 = {0.f,0.f,0.f,0.f};
      const u16* aHp = HB + (size_t)(gb0 + r16) * 512 + q8;
      const u16* b0p = WHH + (size_t)(n0 + r16) * 512 + q8;
      const u16* b1p = WHH + (size_t)(512 + n0 + r16) * 512 + q8;
      const u16* b2p = WHH + (size_t)(1024 + n0 + r16) * 512 + q8;
#pragma unroll 4
      for (int k0 = 0; k0 < 512; k0 += 32) {
        f16x8 a = *(const f16x8*)(aHp + k0);
        a0 = MFMA(a, *(const f16x8*)(b0p + k0), a0);
        a1 = MFMA(a, *(const f16x8*)(b1p + k0), a1);
        a2 = MFMA(a, *(const f16x8*)(b2p + k0), a2);
      }
#pragma unroll
      for (int i = 0; i < 4; ++i) {
        const size_t ro = (size_t)(gb0 + q * 4 + i) * 1536;
        GH[ro + n0 + r16]        = a0[i] + biasH0;
        GH[ro + 512 + n0 + r16]  = a1[i] + biasH1;
        GH[ro + 1024 + n0 + r16] = a2[i] + biasH2;
      }
      flag_arrive(ctrl, FS_GH, tb - 8, tok);
    }

    // ---- all blocks: softmax (own batch) + applied partials from register x ----
    flag_wait(ctrl, FS_S, 8, tok, lane);
    {
      const float2 sv = *(const float2*)(Sf + (size_t)b * 512 + 2 * tid);
      float s0 = sv.x, s1 = sv.y;
      float mx = fmaxf(s0, s1);
#pragma unroll
      for (int off = 32; off; off >>= 1) mx = fmaxf(mx, __shfl_xor(mx, off, 64));
      if (lane == 0) rbuf[warp] = mx;
      __syncthreads();
      mx = fmaxf(fmaxf(rbuf[0], rbuf[1]), fmaxf(rbuf[2], rbuf[3]));
      float e0 = __expf(s0 - mx), e1 = __expf(s1 - mx);
      float sm = e0 + e1;
#pragma unroll
      for (int off = 32; off; off >>= 1) sm += __shfl_xor(sm, off, 64);
      if (lane == 0) rbuf[4 + warp] = sm;
      __syncthreads();
      sm = rbuf[4] + rbuf[5] + rbuf[6] + rbuf[7];
      const float inv = 1.f / sm;
      if ((tid >> 7) == half) {           // this block's m-half: pairs (2m,2m+1)
        h2 pv; pv.x = (_Float16)(e0 * inv); pv.y = (_Float16)(e1 * inv);
        pLDS[tid & 127] = __builtin_bit_cast(u32, pv);
      }
      __syncthreads();

      uint4 pz4[8];
      const uint4* pp = (const uint4*)pLDS + warp * 8;
#pragma unroll
      for (int jj = 0; jj < 8; ++jj) pz4[jj] = pp[jj];
      float accr[8];
#pragma unroll
      for (int r = 0; r < 8; ++r) {
        h2 sA = {(_Float16)0.f, (_Float16)0.f};
        h2 sB = {(_Float16)0.f, (_Float16)0.f};
#pragma unroll
        for (int jj = 0; jj < 8; ++jj) {
          uint4 xw = xr4[r * 8 + jj], pw = pz4[jj];
          sA = __builtin_bit_cast(h2, xw.x) * __builtin_bit_cast(h2, pw.x) + sA;
          sB = __builtin_bit_cast(h2, xw.y) * __builtin_bit_cast(h2, pw.y) + sB;
          sA = __builtin_bit_cast(h2, xw.z) * __builtin_bit_cast(h2, pw.z) + sA;
          sB = __builtin_bit_cast(h2, xw.w) * __builtin_bit_cast(h2, pw.w) + sB;
        }
        accr[r] = (float)sA.x + (float)sA.y + (float)sB.x + (float)sB.y;
      }
#pragma unroll
      for (int r = 0; r < 8; ++r) redbuf[warp * 512 + lane * 8 + r] = accr[r];
      __syncthreads();
      {
        const int tc = tid * 2;
        float v0 = redbuf[tc]     + redbuf[512 + tc]     + redbuf[1024 + tc]     + redbuf[1536 + tc];
        float v1 = redbuf[tc + 1] + redbuf[512 + tc + 1] + redbuf[1024 + tc + 1] + redbuf[1536 + tc + 1];
        float* dst = (half ? AP1 : AP0) + (size_t)b * 512 + tc;
        dst[0] = v0; dst[1] = v1;
      }
      flag_arrive(ctrl, FS_C, tb, tok);
    }

    if (isA) {
      // stage D: g = relu([x(:,t) | applied] @ comb_W^T + comb_b); x-part before C-wait
      f32x4 acc = {0.f, 0.f, 0.f, 0.f};
      const u16* aXp = XT + (size_t)(gb0 + r16) * 262144 + (size_t)t * 512 + q8;
      const u16* bWp = CW + (size_t)(n0 + r16) * 1024 + q8;
#pragma unroll 4
      for (int k0 = 0; k0 < 512; k0 += 32)
        acc = MFMA(*(const f16x8*)(aXp + k0), *(const f16x8*)(bWp + k0), acc);
      flag_wait(ctrl, FS_C, 32, tok, lane);
      const float* a0p = AP0 + (size_t)(gb0 + r16) * 512 + q8;
      const float* a1p = AP1 + (size_t)(gb0 + r16) * 512 + q8;
#pragma unroll 2
      for (int k0 = 0; k0 < 512; k0 += 32) {
        f16x8 af;
#pragma unroll
        for (int c = 0; c < 8; ++c) af[c] = (_Float16)(a0p[k0 + c] + a1p[k0 + c]);
        acc = MFMA(af, *(const f16x8*)(bWp + 512 + k0), acc);
      }
#pragma unroll
      for (int i = 0; i < 4; ++i) {
        float g = fmaxf(acc[i] + biasD, 0.f);
        GB[(size_t)(gb0 + q * 4 + i) * 512 + n0 + r16] = __builtin_bit_cast(u16, (_Float16)g);
      }
      flag_arrive(ctrl, FS_G, tb, tok);
      flag_wait(ctrl, FS_G, 8, tok, lane);

      // stage EF: gi = g @ w_ih^T + b_ih (3 gates), then fused GRU pointwise
      f32x4 g0 = {0.f,0.f,0.f,0.f}, g1 = {0.f,0.f,0.f,0.f}, g2 = {0.f,0.f,0.f,0.f};
      const u16* aGp = GB + (size_t)(gb0 + r16) * 512 + q8;
      const u16* w0p = WIH + (size_t)(n0 + r16) * 512 + q8;
      const u16* w1p = WIH + (size_t)(512 + n0 + r16) * 512 + q8;
      const u16* w2p = WIH + (size_t)(1024 + n0 + r16) * 512 + q8;
#pragma unroll 4
      for (int k0 = 0; k0 < 512; k0 += 32) {
        f16x8 a = *(const f16x8*)(aGp + k0);
        g0 = MFMA(a, *(const f16x8*)(w0p + k0), g0);
        g1 = MFMA(a, *(const f16x8*)(w1p + k0), g1);
        g2 = MFMA(a, *(const f16x8*)(w2p + k0), g2);
      }
      flag_wait(ctrl, FS_GH, 8, tok, lane);
#pragma unroll
      for (int i = 0; i < 4; ++i) {
        const int bi = gb0 + q * 4 + i;
        const size_t ro = (size_t)bi * 1536;
        const int j = n0 + r16;
        float gir = g0[i] + biasI0, giz = g1[i] + biasI1, gin = g2[i] + biasI2;
        float ghr = GH[ro + j], ghz = GH[ro + 512 + j], ghn = GH[ro + 1024 + j];
        float rg = sigmoidf_(gir + ghr);
        float zg = sigmoidf_(giz + ghz);
        float ng = tanhf_(gin + rg * ghn);
        hreg[i] = (1.f - zg) * ng + zg * hreg[i];
        HB[(size_t)bi * 512 + j] = __builtin_bit_cast(u16, (_Float16)hreg[i]);
      }
      flag_arrive(ctrl, FS_H, tb, tok);
    }
  }

  // ---- epilogue: out = h @ out_W^T + out_b ----
  if (isA) {
    flag_wait(ctrl, FS_H, 8, 512u, lane);
    f32x4 acc = {0.f, 0.f, 0.f, 0.f};
    const u16* aHp = HB + (size_t)(gb0 + r16) * 512 + q8;
    const u16* bOp = OW + (size_t)(n0 + r16) * 512 + q8;
#pragma unroll 4
    for (int k0 = 0; k0 < 512; k0 += 32)
      acc = MFMA(*(const f16x8*)(aHp + k0), *(const f16x8*)(bOp + k0), acc);
#pragma unroll
    for (int i = 0; i < 4; ++i)
      out[(size_t)(gb0 + q * 4 + i) * 512 + n0 + r16] = acc[i] + biasO;
  }
}

extern "C" void kernel_launch(void* const* d_in, const int* in_sizes, int n_in,
                              void* d_out, int out_size, void* d_ws, size_t ws_size,
                              hipStream_t stream) {
  if (ws_size < (size_t)WS_NEED) return;
  rnn_fused<<<dim3(256), dim3(256), 0, stream>>>(
      (const float*)d_in[0], (const float*)d_in[1], (const float*)d_in[2],
      (const float*)d_in[3], (const float*)d_in[4], (const float*)d_in[5],
      (const float*)d_in[6], (const float*)d_in[7], (const float*)d_in[8],
      (const float*)d_in[9], (const float*)d_in[10],
      (float*)d_out, (char*)d_ws);
}

// Round 5
// 23193.599 us; speedup vs baseline: 2.3490x; 2.0736x over previous
//
#include <hip/hip_runtime.h>

// Persistent 8-team attention-GRU scan, register-resident x.
// Data path identical to the PASSING 48ms kernel: normal write-back stores,
// flat GH layout. Sync changed asymmetrically:
//   producer: vm drain + barrier + agent RELEASE fence (buffer_wbl2, no inv)
//             + atomicMax token flag
//   consumer: relaxed-agent flag poll, NO acquire fence; reads of hot-written
//             buffers (HB/Sf/AP/GB/GH) use sc0sc1 LOADS (serviced at MALL,
//             where the producer's wbl2 pushed them). Weights/XT stay in L1/L2.

typedef unsigned short u16;
typedef unsigned int u32;
typedef _Float16 h2 __attribute__((ext_vector_type(2)));
typedef _Float16 f16x8 __attribute__((ext_vector_type(8)));
typedef float f32x4 __attribute__((ext_vector_type(4)));
typedef float f32x2 __attribute__((ext_vector_type(2)));
typedef u32 u32x4 __attribute__((ext_vector_type(4)));

#define MAGIC 0x13579BDFu

// ---- workspace layout (bytes) ----
#define OFF_AW   65536      // attn_W f16 [512][1024]
#define OFF_CW   1114112    // comb_W f16 [512][1024]
#define OFF_WIH  2162688    // w_ih  f16 [1536][512]
#define OFF_WHH  3735552    // w_hh  f16 [1536][512]
#define OFF_OW   5308416    // out_W f16 [512][512]
#define OFF_HB   5832704    // h f16 [128][512]
#define OFF_SF   5963776    // scores f32 [128][512]
#define OFF_AP0  6225920    // applied half0 partial f32 [128][512]
#define OFF_AP1  6488064    // applied half1 partial f32 [128][512]
#define OFF_GB   6750208    // g f16 [128][512]
#define OFF_GH   6881280    // gh f32 [128][1536] (flat, as in passing kernel)
#define OFF_XT   7667712    // x^T f16 [128 b][512 t][512 m]  64 MiB
#define WS_NEED  74776576

// flag slot bases (u32 index into per-team ctrl[1024])
#define FS_S   64
#define FS_C   96
#define FS_G   128
#define FS_GH  160
#define FS_H   192
#define FS_RDY 224

__device__ __forceinline__ float sigmoidf_(float v) { return 1.f / (1.f + __expf(-v)); }
__device__ __forceinline__ float tanhf_(float v) {
  v = fminf(fmaxf(v, -15.f), 15.f);
  float e2 = __expf(2.f * v);
  return (e2 - 1.f) / (e2 + 1.f);
}
__device__ __forceinline__ u32 packh2(float a, float b) {
  h2 v; v.x = (_Float16)a; v.y = (_Float16)b;
  return __builtin_bit_cast(u32, v);
}

__device__ __forceinline__ void vm_drain() { asm volatile("s_waitcnt vmcnt(0)" ::: "memory"); }

// ---- coherent (sc0 sc1) LOAD helpers only — no coherent stores anywhere ----
__device__ __forceinline__ f32x2 ldg_f32x2(const void* p) {
  f32x2 r;
  asm volatile("global_load_dwordx2 %0, %1, off sc0 sc1\n\ts_waitcnt vmcnt(0)"
               : "=v"(r) : "v"(p) : "memory");
  return r;
}
__device__ __forceinline__ void ldg4x16(const void* p0, const void* p1, const void* p2,
                                        const void* p3, u32x4& a, u32x4& b, u32x4& c, u32x4& d) {
  asm volatile(
      "global_load_dwordx4 %0, %4, off sc0 sc1\n\t"
      "global_load_dwordx4 %1, %5, off sc0 sc1\n\t"
      "global_load_dwordx4 %2, %6, off sc0 sc1\n\t"
      "global_load_dwordx4 %3, %7, off sc0 sc1\n\t"
      "s_waitcnt vmcnt(0)"
      : "=&v"(a), "=&v"(b), "=&v"(c), "=&v"(d)
      : "v"(p0), "v"(p1), "v"(p2), "v"(p3) : "memory");
}
__device__ __forceinline__ void ldg3_f32(const float* p0, const float* p1, const float* p2,
                                         float& a, float& b, float& c) {
  asm volatile(
      "global_load_dword %0, %3, off sc0 sc1\n\t"
      "global_load_dword %1, %4, off sc0 sc1\n\t"
      "global_load_dword %2, %5, off sc0 sc1\n\t"
      "s_waitcnt vmcnt(0)"
      : "=&v"(a), "=&v"(b), "=&v"(c)
      : "v"(p0), "v"(p1), "v"(p2) : "memory");
}

// producer: waves drain stores (compiler emits vmcnt(0) before s_barrier),
// then tid0: agent-release fence (buffer_wbl2 -> MALL, NO invalidate) + flag.
__device__ __forceinline__ void flag_arrive(u32* ctrl, int fs, int slot, u32 tok) {
  vm_drain();
  __syncthreads();
  if (threadIdx.x == 0) {
    __builtin_amdgcn_fence(__ATOMIC_RELEASE, "agent");
    atomicMax(ctrl + fs + slot, tok);
  }
}
// consumer: all-wave relaxed-agent poll. NO acquire fence (no cached reads of
// produced data; all such reads are sc0sc1 loads).
__device__ __forceinline__ void flag_wait(u32* ctrl, int fs, int n, u32 tok, int lane) {
  if (tok == 0u) return;
  u32* p = ctrl + fs;
  for (;;) {
    u32 v = tok;
    if (lane < n) v = __hip_atomic_load(p + lane, __ATOMIC_RELAXED, __HIP_MEMORY_SCOPE_AGENT);
    if (__all((int)(v >= tok))) break;
  }
}

// stage 16 rows x 512 f16 (coherent loads) -> LDS rows, stride 520 f16 (1040 B)
__device__ __forceinline__ void stage_rows(const u16* gsrc, char* lds, int tid) {
  const int row = tid >> 4, c = tid & 15;
  const u16* g = gsrc + row * 512 + c * 32;
  u32x4 a, b, cc, d;
  ldg4x16(g, g + 8, g + 16, g + 24, a, b, cc, d);
  u32x4* dst = (u32x4*)(lds + row * 1040 + c * 64);
  dst[0] = a; dst[1] = b; dst[2] = cc; dst[3] = d;
}

#define MFMA(a, b, c) __builtin_amdgcn_mfma_f32_16x16x32_f16((a), (b), (c), 0, 0, 0)

extern "C" __global__ void __launch_bounds__(256, 1)
rnn_fused(const float* __restrict__ x, const float* __restrict__ attn_W,
          const float* __restrict__ attn_b, const float* __restrict__ comb_W,
          const float* __restrict__ comb_b, const float* __restrict__ w_ih,
          const float* __restrict__ w_hh, const float* __restrict__ b_ih,
          const float* __restrict__ b_hh, const float* __restrict__ out_W,
          const float* __restrict__ out_b, float* __restrict__ out,
          char* __restrict__ ws)
{
  const int tid  = threadIdx.x;
  const int lane = tid & 63;
  const int warp = tid >> 6;
  const int team = blockIdx.x & 7;
  const int tb   = blockIdx.x >> 3;     // 0..31 within team
  const int tt   = tb * 256 + tid;      // team thread id
  const int gb0  = team * 16;
  const int lb   = tb >> 1;             // pair index -> batch
  const int half = tb & 1;              // m-half of x held by this block
  const int b    = gb0 + lb;            // this block's batch (x holder / stage C)
  const int m0h  = half * 256;

  u32* ctrl = (u32*)ws + team * 1024;   // 4 KB per team

  u16*   AW  = (u16*)(ws + OFF_AW);
  u16*   CW  = (u16*)(ws + OFF_CW);
  u16*   WIH = (u16*)(ws + OFF_WIH);
  u16*   WHH = (u16*)(ws + OFF_WHH);
  u16*   OW  = (u16*)(ws + OFF_OW);
  u16*   HB  = (u16*)(ws + OFF_HB);
  float* Sf  = (float*)(ws + OFF_SF);
  float* AP0 = (float*)(ws + OFF_AP0);
  float* AP1 = (float*)(ws + OFF_AP1);
  u16*   GB  = (u16*)(ws + OFF_GB);
  float* GH  = (float*)(ws + OFF_GH);
  u16*   XT  = (u16*)(ws + OFF_XT);

  __shared__ char smem[16704];
  float*     tbuf   = (float*)smem;           // [64][65] f32, init transpose only
  u32*       pLDS   = (u32*)smem;             // [128] packed f16 p-pairs (stage C)
  float*     redbuf = (float*)(smem + 512);   // [4][512] stage C partials
  float*     rbuf   = (float*)(smem + 8704);  // [8] softmax reduce scratch
  _Float16*  ldsF   = (_Float16*)smem;        // staged fragments, row stride 520

  // ---- init handshake (per team): block 0 zeroes ctrl, sets magic ----
  if (tb == 0) {
    for (int i = 1 + tid; i < 1024; i += 256) ctrl[i] = 0u;
    __syncthreads();
    if (tid == 0) { __threadfence(); atomicExch(ctrl, MAGIC); }
  }
  if (tid == 0) {
    while (__hip_atomic_load(ctrl, __ATOMIC_RELAXED, __HIP_MEMORY_SCOPE_AGENT) != MAGIC) {}
    __threadfence();
  }
  __syncthreads();

  // ---- phase 0a: weights -> f16 (team-redundant, same-value benign races) ----
  for (int i = tt; i < 512 * 1024; i += 8192) AW[i]  = __builtin_bit_cast(u16, (_Float16)attn_W[i]);
  for (int i = tt; i < 512 * 1024; i += 8192) CW[i]  = __builtin_bit_cast(u16, (_Float16)comb_W[i]);
  for (int i = tt; i < 1536 * 512; i += 8192) WIH[i] = __builtin_bit_cast(u16, (_Float16)w_ih[i]);
  for (int i = tt; i < 1536 * 512; i += 8192) WHH[i] = __builtin_bit_cast(u16, (_Float16)w_hh[i]);
  for (int i = tt; i < 512 * 512;  i += 8192) OW[i]  = __builtin_bit_cast(u16, (_Float16)out_W[i]);
  HB[(size_t)gb0 * 512 + tt] = 0;   // h0 = 0

  // ---- phase 0b: transpose this block's m-half of x[b] into XT[b][t][m] (f16) ----
  {
    const float* xb  = x  + (size_t)b * 512 * 512;
    u16*         xtB = XT + (size_t)b * 512 * 512;
    for (int mt = 0; mt < 4; ++mt) {
      for (int ct = 0; ct < 8; ++ct) {
        for (int rr = warp; rr < 64; rr += 4)
          tbuf[rr * 65 + lane] = xb[(size_t)(m0h + mt * 64 + rr) * 512 + ct * 64 + lane];
        __syncthreads();
        for (int rr = warp; rr < 64; rr += 4)
          xtB[(size_t)(ct * 64 + rr) * 512 + m0h + mt * 64 + lane] =
              __builtin_bit_cast(u16, (_Float16)tbuf[lane * 65 + rr]);
        __syncthreads();
      }
    }
  }

  // init release (full fence: pushes weights/XT/HB to MALL), RDY, one-time acquire
  vm_drain();
  __syncthreads();
  if (tid == 0) { __threadfence(); atomicMax(ctrl + FS_RDY + tb, 1u); }
  {
    u32* p = ctrl + FS_RDY;
    for (;;) {
      u32 v = 1u;
      if (lane < 32) v = __hip_atomic_load(p + lane, __ATOMIC_RELAXED, __HIP_MEMORY_SCOPE_AGENT);
      if (__all((int)(v >= 1u))) break;
    }
  }
  __syncthreads();
  __threadfence();   // one-time acquire: L1/L2 inv so normal XT/weight loads are fresh

  // ---- phase 0c: register-resident x: rows t=lane*8+r, cols m0h+warp*64.. ----
  uint4 xr4[64];
  {
    const u16* base = XT + (size_t)b * 262144 + m0h + warp * 64;
#pragma unroll
    for (int r = 0; r < 8; ++r) {
      const uint4* row = (const uint4*)(base + (size_t)(lane * 8 + r) * 512);
#pragma unroll
      for (int jj = 0; jj < 8; ++jj) xr4[r * 8 + jj] = row[jj];
    }
  }

  const int  r16 = lane & 15, q = lane >> 4, q8 = q * 8;
  const bool isA = (tb < 8), isW = (tb >= 8 && tb < 16);
  const int  W4 = ((tb < 8) ? tb : tb - 8) * 4 + warp;
  const int  n0 = W4 * 16;

  float biasA = 0.f, biasD = 0.f, biasI0 = 0.f, biasI1 = 0.f, biasI2 = 0.f,
        biasH0 = 0.f, biasH1 = 0.f, biasH2 = 0.f, biasO = 0.f;
  if (isA) {
    biasA = attn_b[n0 + r16]; biasD = comb_b[n0 + r16];
    biasI0 = b_ih[n0 + r16]; biasI1 = b_ih[512 + n0 + r16]; biasI2 = b_ih[1024 + n0 + r16];
    biasO = out_b[n0 + r16];
  }
  if (isW) {
    biasH0 = b_hh[n0 + r16]; biasH1 = b_hh[512 + n0 + r16]; biasH2 = b_hh[1024 + n0 + r16];
  }

  float hreg[4] = {0.f, 0.f, 0.f, 0.f};

  for (int t = 0; t < 512; ++t) {
    const u32 tok = (u32)(t + 1);

    if (isA) {
      flag_wait(ctrl, FS_H, 8, (u32)t, lane);
      __syncthreads();                         // all waves past wait before LDS reuse
      stage_rows(HB + gb0 * 512, smem, tid);   // coherent h -> LDS
      __syncthreads();
      // stage A: S = [x(:,t) | h] @ attn_W^T + attn_b
      f32x4 acc = {0.f, 0.f, 0.f, 0.f};
      const u16* aXp = XT + (size_t)(gb0 + r16) * 262144 + (size_t)t * 512 + q8;
      const _Float16* aHl = ldsF + r16 * 520 + q8;
      const u16* bWp = AW + (size_t)(n0 + r16) * 1024 + q8;
#pragma unroll 4
      for (int k0 = 0; k0 < 512; k0 += 32)
        acc = MFMA(*(const f16x8*)(aXp + k0), *(const f16x8*)(bWp + k0), acc);
#pragma unroll 4
      for (int k0 = 0; k0 < 512; k0 += 32)
        acc = MFMA(*(const f16x8*)(aHl + k0), *(const f16x8*)(bWp + 512 + k0), acc);
#pragma unroll
      for (int i = 0; i < 4; ++i)
        Sf[(size_t)(gb0 + q * 4 + i) * 512 + n0 + r16] = acc[i] + biasA;   // normal store
      flag_arrive(ctrl, FS_S, tb, tok);
    } else if (isW) {
      flag_wait(ctrl, FS_H, 8, (u32)t, lane);
      __syncthreads();
      stage_rows(HB + gb0 * 512, smem, tid);
      __syncthreads();
      // gh = h @ w_hh^T + b_hh (3 gate tiles, shared A-fragment)
      f32x4 a0 = {0.f,0.f,0.f,0.f}, a1 = {0.f,0.f,0.f,0.f}, a2 = {0.f,0.f,0.f,0.f};
      const _Float16* aHl = ldsF + r16 * 520 + q8;
      const u16* b0p = WHH + (size_t)(n0 + r16) * 512 + q8;
      const u16* b1p = WHH + (size_t)(512 + n0 + r16) * 512 + q8;
      const u16* b2p = WHH + (size_t)(1024 + n0 + r16) * 512 + q8;
#pragma unroll 4
      for (int k0 = 0; k0 < 512; k0 += 32) {
        f16x8 a = *(const f16x8*)(aHl + k0);
        a0 = MFMA(a, *(const f16x8*)(b0p + k0), a0);
        a1 = MFMA(a, *(const f16x8*)(b1p + k0), a1);
        a2 = MFMA(a, *(const f16x8*)(b2p + k0), a2);
      }
#pragma unroll
      for (int i = 0; i < 4; ++i) {            // normal stores, flat layout
        const size_t ro = (size_t)(gb0 + q * 4 + i) * 1536;
        GH[ro + n0 + r16]        = a0[i] + biasH0;
        GH[ro + 512 + n0 + r16]  = a1[i] + biasH1;
        GH[ro + 1024 + n0 + r16] = a2[i] + biasH2;
      }
      flag_arrive(ctrl, FS_GH, tb - 8, tok);
    }

    // ---- all blocks: softmax (own batch) + applied partials from register x ----
    flag_wait(ctrl, FS_S, 8, tok, lane);
    {
      const int tc = 2 * tid;
      f32x2 sv = ldg_f32x2(Sf + (size_t)b * 512 + tc);   // coherent read
      float s0 = sv.x, s1 = sv.y;
      float mx = fmaxf(s0, s1);
#pragma unroll
      for (int off = 32; off; off >>= 1) mx = fmaxf(mx, __shfl_xor(mx, off, 64));
      if (lane == 0) rbuf[warp] = mx;
      __syncthreads();
      mx = fmaxf(fmaxf(rbuf[0], rbuf[1]), fmaxf(rbuf[2], rbuf[3]));
      float e0 = __expf(s0 - mx), e1 = __expf(s1 - mx);
      float sm = e0 + e1;
#pragma unroll
      for (int off = 32; off; off >>= 1) sm += __shfl_xor(sm, off, 64);
      if (lane == 0) rbuf[4 + warp] = sm;
      __syncthreads();
      sm = rbuf[4] + rbuf[5] + rbuf[6] + rbuf[7];
      const float inv = 1.f / sm;
      if ((tid >> 7) == half) {
        pLDS[tid & 127] = packh2(e0 * inv, e1 * inv);
      }
      __syncthreads();

      uint4 pz4[8];
      const uint4* pp = (const uint4*)pLDS + warp * 8;
#pragma unroll
      for (int jj = 0; jj < 8; ++jj) pz4[jj] = pp[jj];
      float accr[8];
#pragma unroll
      for (int r = 0; r < 8; ++r) {
        h2 sA = {(_Float16)0.f, (_Float16)0.f};
        h2 sB = {(_Float16)0.f, (_Float16)0.f};
#pragma unroll
        for (int jj = 0; jj < 8; ++jj) {
          uint4 xw = xr4[r * 8 + jj], pw = pz4[jj];
          sA = __builtin_bit_cast(h2, xw.x) * __builtin_bit_cast(h2, pw.x) + sA;
          sB = __builtin_bit_cast(h2, xw.y) * __builtin_bit_cast(h2, pw.y) + sB;
          sA = __builtin_bit_cast(h2, xw.z) * __builtin_bit_cast(h2, pw.z) + sA;
          sB = __builtin_bit_cast(h2, xw.w) * __builtin_bit_cast(h2, pw.w) + sB;
        }
        accr[r] = (float)sA.x + (float)sA.y + (float)sB.x + (float)sB.y;
      }
#pragma unroll
      for (int r = 0; r < 8; ++r) redbuf[warp * 512 + lane * 8 + r] = accr[r];
      __syncthreads();
      {
        float v0 = redbuf[tc]     + redbuf[512 + tc]     + redbuf[1024 + tc]     + redbuf[1536 + tc];
        float v1 = redbuf[tc + 1] + redbuf[512 + tc + 1] + redbuf[1024 + tc + 1] + redbuf[1536 + tc + 1];
        float* dst = (half ? AP1 : AP0) + (size_t)b * 512 + tc;   // normal stores
        dst[0] = v0; dst[1] = v1;
      }
      flag_arrive(ctrl, FS_C, tb, tok);
    }

    if (isA) {
      // stage D: g = relu([x(:,t) | applied] @ comb_W^T + comb_b); x-part first
      f32x4 acc = {0.f, 0.f, 0.f, 0.f};
      const u16* aXp = XT + (size_t)(gb0 + r16) * 262144 + (size_t)t * 512 + q8;
      const u16* bWp = CW + (size_t)(n0 + r16) * 1024 + q8;
#pragma unroll 4
      for (int k0 = 0; k0 < 512; k0 += 32)
        acc = MFMA(*(const f16x8*)(aXp + k0), *(const f16x8*)(bWp + k0), acc);
      flag_wait(ctrl, FS_C, 32, tok, lane);
      __syncthreads();
      {  // stage applied = AP0+AP1 (coherent f32 reads) -> f16 LDS rows
        const int row = tid >> 4, c = tid & 15;
        const float* g0 = AP0 + (size_t)(gb0 + row) * 512 + c * 32;
        const float* g1 = AP1 + (size_t)(gb0 + row) * 512 + c * 32;
        u32* dst = (u32*)(smem + row * 1040 + c * 64);
        u32x4 A0, A1, A2, A3, B0, B1, B2, B3, C0, C1, C2, C3, D0, D1, D2, D3;
        ldg4x16(g0,      g0 + 4,  g0 + 8,  g0 + 12, A0, A1, A2, A3);
        ldg4x16(g0 + 16, g0 + 20, g0 + 24, g0 + 28, B0, B1, B2, B3);
        ldg4x16(g1,      g1 + 4,  g1 + 8,  g1 + 12, C0, C1, C2, C3);
        ldg4x16(g1 + 16, g1 + 20, g1 + 24, g1 + 28, D0, D1, D2, D3);
        f32x4 s0 = __builtin_bit_cast(f32x4, A0) + __builtin_bit_cast(f32x4, C0);
        f32x4 s1 = __builtin_bit_cast(f32x4, A1) + __builtin_bit_cast(f32x4, C1);
        f32x4 s2 = __builtin_bit_cast(f32x4, A2) + __builtin_bit_cast(f32x4, C2);
        f32x4 s3 = __builtin_bit_cast(f32x4, A3) + __builtin_bit_cast(f32x4, C3);
        f32x4 s4 = __builtin_bit_cast(f32x4, B0) + __builtin_bit_cast(f32x4, D0);
        f32x4 s5 = __builtin_bit_cast(f32x4, B1) + __builtin_bit_cast(f32x4, D1);
        f32x4 s6 = __builtin_bit_cast(f32x4, B2) + __builtin_bit_cast(f32x4, D2);
        f32x4 s7 = __builtin_bit_cast(f32x4, B3) + __builtin_bit_cast(f32x4, D3);
        dst[0]  = packh2(s0[0], s0[1]); dst[1]  = packh2(s0[2], s0[3]);
        dst[2]  = packh2(s1[0], s1[1]); dst[3]  = packh2(s1[2], s1[3]);
        dst[4]  = packh2(s2[0], s2[1]); dst[5]  = packh2(s2[2], s2[3]);
        dst[6]  = packh2(s3[0], s3[1]); dst[7]  = packh2(s3[2], s3[3]);
        dst[8]  = packh2(s4[0], s4[1]); dst[9]  = packh2(s4[2], s4[3]);
        dst[10] = packh2(s5[0], s5[1]); dst[11] = packh2(s5[2], s5[3]);
        dst[12] = packh2(s6[0], s6[1]); dst[13] = packh2(s6[2], s6[3]);
        dst[14] = packh2(s7[0], s7[1]); dst[15] = packh2(s7[2], s7[3]);
      }
      __syncthreads();
      const _Float16* aAl = ldsF + r16 * 520 + q8;
#pragma unroll 4
      for (int k0 = 0; k0 < 512; k0 += 32)
        acc = MFMA(*(const f16x8*)(aAl + k0), *(const f16x8*)(bWp + 512 + k0), acc);
#pragma unroll
      for (int i = 0; i < 4; ++i) {
        float g = fmaxf(acc[i] + biasD, 0.f);
        GB[(size_t)(gb0 + q * 4 + i) * 512 + n0 + r16] =
            __builtin_bit_cast(u16, (_Float16)g);   // normal store
      }
      flag_arrive(ctrl, FS_G, tb, tok);
      flag_wait(ctrl, FS_G, 8, tok, lane);
      __syncthreads();
      stage_rows(GB + gb0 * 512, smem, tid);   // coherent g -> LDS
      __syncthreads();

      // stage EF: gi = g @ w_ih^T + b_ih (3 gates), then fused GRU pointwise
      f32x4 g0 = {0.f,0.f,0.f,0.f}, g1 = {0.f,0.f,0.f,0.f}, g2 = {0.f,0.f,0.f,0.f};
      const _Float16* aGl = ldsF + r16 * 520 + q8;
      const u16* w0p = WIH + (size_t)(n0 + r16) * 512 + q8;
      const u16* w1p = WIH + (size_t)(512 + n0 + r16) * 512 + q8;
      const u16* w2p = WIH + (size_t)(1024 + n0 + r16) * 512 + q8;
#pragma unroll 4
      for (int k0 = 0; k0 < 512; k0 += 32) {
        f16x8 a = *(const f16x8*)(aGl + k0);
        g0 = MFMA(a, *(const f16x8*)(w0p + k0), g0);
        g1 = MFMA(a, *(const f16x8*)(w1p + k0), g1);
        g2 = MFMA(a, *(const f16x8*)(w2p + k0), g2);
      }
      flag_wait(ctrl, FS_GH, 8, tok, lane);
#pragma unroll
      for (int i = 0; i < 4; ++i) {
        const int bi = gb0 + q * 4 + i;
        const size_t ro = (size_t)bi * 1536;
        const int j = n0 + r16;
        float ghr_, ghz_, ghn_;
        ldg3_f32(GH + ro + j, GH + ro + 512 + j, GH + ro + 1024 + j, ghr_, ghz_, ghn_);
        float gir = g0[i] + biasI0, giz = g1[i] + biasI1, gin = g2[i] + biasI2;
        float rg = sigmoidf_(gir + ghr_);
        float zg = sigmoidf_(giz + ghz_);
        float ng = tanhf_(gin + rg * ghn_);
        hreg[i] = (1.f - zg) * ng + zg * hreg[i];
        HB[(size_t)bi * 512 + j] = __builtin_bit_cast(u16, (_Float16)hreg[i]);  // normal
      }
      flag_arrive(ctrl, FS_H, tb, tok);
    }
  }

  // ---- epilogue: out = h @ out_W^T + out_b ----
  if (isA) {
    flag_wait(ctrl, FS_H, 8, 512u, lane);
    __syncthreads();
    stage_rows(HB + gb0 * 512, smem, tid);
    __syncthreads();
    f32x4 acc = {0.f, 0.f, 0.f, 0.f};
    const _Float16* aHl = ldsF + r16 * 520 + q8;
    const u16* bOp = OW + (size_t)(n0 + r16) * 512 + q8;
#pragma unroll 4
    for (int k0 = 0; k0 < 512; k0 += 32)
      acc = MFMA(*(const f16x8*)(aHl + k0), *(const f16x8*)(bOp + k0), acc);
#pragma unroll
    for (int i = 0; i < 4; ++i)
      out[(size_t)(gb0 + q * 4 + i) * 512 + n0 + r16] = acc[i] + biasO;
  }
}

extern "C" void kernel_launch(void* const* d_in, const int* in_sizes, int n_in,
                              void* d_out, int out_size, void* d_ws, size_t ws_size,
                              hipStream_t stream) {
  if (ws_size < (size_t)WS_NEED) return;
  rnn_fused<<<dim3(256), dim3(256), 0, stream>>>(
      (const float*)d_in[0], (const float*)d_in[1], (const float*)d_in[2],
      (const float*)d_in[3], (const float*)d_in[4], (const float*)d_in[5],
      (const float*)d_in[6], (const float*)d_in[7], (const float*)d_in[8],
      (const float*)d_in[9], (const float*)d_in[10],
      (float*)d_out, (char*)d_ws);
}